// Round 12
// baseline (140.747 us; speedup 1.0000x reference)
//
#include <hip/hip_runtime.h>
#include <math.h>

typedef unsigned short ushort_t;
typedef __attribute__((ext_vector_type(8))) short bf16x8;
typedef __attribute__((ext_vector_type(4))) float f32x4;

#define CHK 67200            // chunk plane stride in ushorts (8400 anchors * 8 ch)
#define IMG6 403200          // per-image buffer: 6 primary chunks only

__device__ __forceinline__ float relu6f(float x){ return fminf(fmaxf(x,0.f),6.f); }
__device__ __forceinline__ float sigmoidf(float x){ return 1.f/(1.f+__expf(-x)); }
__device__ __forceinline__ float bf2f(unsigned u){ union{unsigned i; float f;}v; v.i=u<<16; return v.f; }
__device__ __forceinline__ unsigned f2bf(float f){ union{float f; unsigned i;}v; v.f=f;
    unsigned r = v.i + 0x7fff + ((v.i>>16)&1); return r>>16; }
__device__ __forceinline__ bf16x8 ldb8(const ushort_t* p){ return *reinterpret_cast<const bf16x8*>(p); }
// load 8 consecutive fp32 weights -> packed bf16x8 (same RNE rounding as prep did)
__device__ __forceinline__ bf16x8 ld8f(const float* __restrict__ p){
    union { unsigned u[4]; bf16x8 v; } cv;
    #pragma unroll
    for (int j=0;j<4;j++) cv.u[j] = f2bf(p[2*j]) | (f2bf(p[2*j+1])<<16);
    return cv.v;
}
#define MFMA(a,b,c) __builtin_amdgcn_mfma_f32_16x16x32_bf16((a),(b),(c),0,0,0)

// ---------------------------------------------------------------------------
// Tile decode: 67 blocks of 128 anchors (50 lev0 / 13 lev1 / 4 lev2).
// ---------------------------------------------------------------------------
__device__ __forceinline__ void tile_decode(int bx, int& lev, int& pb, int& HW,
                                            int& W, int& aoff, int& nt)
{
    if (bx < 50){ lev=0; pb = bx*128;      HW=6400; W=80; aoff=0;    }
    else if (bx < 63){ lev=1; pb = (bx-50)*128; HW=1600; W=40; aoff=6400; }
    else { lev=2; pb = (bx-63)*128; HW=400; W=20; aoff=8000; }
    nt = HW - pb; if (nt > 128) nt = 128;
}

// ---------------------------------------------------------------------------
// dw stage: 3x3 depthwise on 6 primary chunks of X (global, halo ok) for a
// 128-anchor tile -> cheap 48ch into LDS xs[a][56] (slots 0..5 of 8ch).
// 192 threads active: ck = tid>>5 (chunk), q = tid&31 (anchor quad).
// ---------------------------------------------------------------------------
__device__ __forceinline__ void dw_stage(
    const ushort_t* __restrict__ X, ushort_t* __restrict__ xs,
    const float* __restrict__ cheap_w,
    const float* __restrict__ bn2_s, const float* __restrict__ bn2_b,
    int pl, int lev, int pb, int W, int aoff, int nt, int tid)
{
    int ck = tid >> 5;          // 0..7 (6 used)
    int q  = tid & 31;
    if (ck >= 6 || q*4 >= nt) return;
    int p = pb + q*4;
    int h = (lev==0) ? p/80 : (lev==1) ? p/40 : p/20;
    int x0 = p - h*W;           // multiple of 4; 4 anchors same row
    int s8 = ck*8;
    const ushort_t* src = X + (size_t)ck*CHK + (size_t)(aoff+p)*8;

    float acc[4][8];
    #pragma unroll
    for (int j=0;j<4;j++)
        #pragma unroll
        for (int c=0;c<8;c++) acc[j][c] = 0.f;

    #pragma unroll
    for (int dy=-1; dy<=1; dy++){
        int hh = h + dy;
        bool rv = (unsigned)hh < (unsigned)W;    // H == W (square levels)
        float xv[6][8];
        #pragma unroll
        for (int i=0;i<6;i++){
            int px = x0 + i - 1;
            bool v = rv && ((unsigned)px < (unsigned)W);
            ptrdiff_t off = v ? (ptrdiff_t)(dy*W + i - 1)*8 : 0;    // address select
            uint4 u = *reinterpret_cast<const uint4*>(src + off);   // unconditional
            u.x = v ? u.x : 0u; u.y = v ? u.y : 0u;
            u.z = v ? u.z : 0u; u.w = v ? u.w : 0u;
            xv[i][0]=bf2f(u.x&0xffffu); xv[i][1]=bf2f(u.x>>16);
            xv[i][2]=bf2f(u.y&0xffffu); xv[i][3]=bf2f(u.y>>16);
            xv[i][4]=bf2f(u.z&0xffffu); xv[i][5]=bf2f(u.z>>16);
            xv[i][6]=bf2f(u.w&0xffffu); xv[i][7]=bf2f(u.w>>16);
        }
        #pragma unroll
        for (int c=0;c<8;c++){
            float w0 = cheap_w[(pl*48 + s8 + c)*9 + (dy+1)*3 + 0];
            float w1 = cheap_w[(pl*48 + s8 + c)*9 + (dy+1)*3 + 1];
            float w2 = cheap_w[(pl*48 + s8 + c)*9 + (dy+1)*3 + 2];
            #pragma unroll
            for (int j=0;j<4;j++)
                acc[j][c] = fmaf(xv[j][c], w0,
                            fmaf(xv[j+1][c], w1,
                            fmaf(xv[j+2][c], w2, acc[j][c])));
        }
    }

    float s2v[8], b2v[8];
    #pragma unroll
    for (int c=0;c<8;c++){
        s2v[c] = bn2_s[pl*48 + s8 + c];
        b2v[c] = bn2_b[pl*48 + s8 + c];
    }
    #pragma unroll
    for (int j=0;j<4;j++){
        uint4 o;
        o.x = f2bf(relu6f(fmaf(acc[j][0], s2v[0], b2v[0])))
           | (f2bf(relu6f(fmaf(acc[j][1], s2v[1], b2v[1]))) << 16);
        o.y = f2bf(relu6f(fmaf(acc[j][2], s2v[2], b2v[2])))
           | (f2bf(relu6f(fmaf(acc[j][3], s2v[3], b2v[3]))) << 16);
        o.z = f2bf(relu6f(fmaf(acc[j][4], s2v[4], b2v[4])))
           | (f2bf(relu6f(fmaf(acc[j][5], s2v[5], b2v[5]))) << 16);
        o.w = f2bf(relu6f(fmaf(acc[j][6], s2v[6], b2v[6])))
           | (f2bf(relu6f(fmaf(acc[j][7], s2v[7], b2v[7]))) << 16);
        *reinterpret_cast<uint4*>(xs + (size_t)(q*4+j)*56 + s8) = o;
    }
}

// B-fragment gather: primary from global chunks, cheap from LDS.
__device__ __forceinline__ void gather_B(
    const ushort_t* __restrict__ X, const ushort_t* __restrict__ xs,
    int a_l, size_t A_g, int rg, bf16x8* Bf)
{
    Bf[0] = ldb8(X + (size_t)rg*CHK + A_g*8);
    Bf[1] = (rg < 2) ? ldb8(X + (size_t)(4+rg)*CHK + A_g*8)
                     : ldb8(xs + (size_t)a_l*56 + (rg-2)*8);
    Bf[2] = ldb8(xs + (size_t)a_l*56 + 16 + rg*8);
}

// ---------------------------------------------------------------------------
// Layer-0 pointwise via MFMA, LDS-free gather from CHW fp32.
// grid (132, bc), block 256; ONE 16-anchor tile per wave. Weights converted
// in-register from fp32 (L2-hot; identical rounding to the old prep pass).
// Output: 6 primary chunks of C0/R0.
// ---------------------------------------------------------------------------
__global__ __launch_bounds__(256) void pw0_kernel(
    const float* __restrict__ f0, const float* __restrict__ f1, const float* __restrict__ f2,
    ushort_t* __restrict__ Oc, ushort_t* __restrict__ Or,
    const float* __restrict__ primary_w,
    const float* __restrict__ bn1_s, const float* __restrict__ bn1_b, int b0)
{
    int lane = threadIdx.x & 63, wv = threadIdx.x >> 6;
    int l15 = lane & 15, rg = lane >> 4;
    int by = blockIdx.y;

    int t = blockIdx.x*4 + wv;          // one tile per wave
    if (t >= 525) return;

    bf16x8 A[2][3][3];
    #pragma unroll
    for (int br=0;br<2;br++)
        #pragma unroll
        for (int ot=0; ot<3; ot++)
            #pragma unroll
            for (int kt=0; kt<3; kt++)
                A[br][ot][kt] = ld8f(primary_w
                    + (size_t)((br*2)*48 + ot*16 + l15)*96 + kt*32 + rg*8);

    int lev  = (t < 400) ? 0 : (t < 500) ? 1 : 2;
    int HW   = (lev==0) ? 6400 : (lev==1) ? 1600 : 400;
    int tb   = (lev==0) ? 0    : (lev==1) ? 400  : 500;
    int aoff = (lev==0) ? 0    : (lev==1) ? 6400 : 8000;
    int p0   = (t - tb)*16;
    const float* fb = ((lev==0)? f0 : (lev==1)? f1 : f2)
                    + (size_t)(b0+by)*96*HW + p0 + l15;

    bf16x8 Bf[3];
    #pragma unroll
    for (int kt=0;kt<3;kt++){
        const float* fc = fb + (size_t)(kt*32 + rg*8)*HW;
        float x[8];
        #pragma unroll
        for (int j=0;j<8;j++) x[j] = fc[(size_t)j*HW];
        union { unsigned u[4]; bf16x8 v; } cv;
        #pragma unroll
        for (int j=0;j<4;j++) cv.u[j] = f2bf(x[2*j]) | (f2bf(x[2*j+1])<<16);
        Bf[kt] = cv.v;
    }

    size_t A_g = (size_t)(aoff + p0 + l15);
    #pragma unroll
    for (int br=0;br<2;br++){
        int pl = br*2;
        f32x4 acc[3];
        #pragma unroll
        for (int ot=0;ot<3;ot++){ acc[ot][0]=0.f; acc[ot][1]=0.f; acc[ot][2]=0.f; acc[ot][3]=0.f; }
        #pragma unroll
        for (int kt=0;kt<3;kt++)
            #pragma unroll
            for (int ot=0;ot<3;ot++)
                acc[ot] = MFMA(A[br][ot][kt], Bf[kt], acc[ot]);
        ushort_t* obase = (br ? Or : Oc) + (size_t)by*IMG6;
        #pragma unroll
        for (int ot=0;ot<3;ot++){
            f32x4 sv4 = *reinterpret_cast<const f32x4*>(bn1_s + pl*48 + ot*16 + rg*4);
            f32x4 bv4 = *reinterpret_cast<const f32x4*>(bn1_b + pl*48 + ot*16 + rg*4);
            uint2 u;
            u.x = f2bf(relu6f(fmaf(acc[ot][0], sv4[0], bv4[0])))
               | (f2bf(relu6f(fmaf(acc[ot][1], sv4[1], bv4[1]))) << 16);
            u.y = f2bf(relu6f(fmaf(acc[ot][2], sv4[2], bv4[2])))
               | (f2bf(relu6f(fmaf(acc[ot][3], sv4[3], bv4[3]))) << 16);
            int chunk = 2*ot + (rg>>1);
            *reinterpret_cast<uint2*>(obase + (size_t)chunk*CHK + A_g*8 + (rg&1)*4) = u;
        }
    }
}

// ---------------------------------------------------------------------------
// Fused dw(layer0) + pw(layer1). grid (67, bc, 2), block 256.
// Phase 1: dw -> LDS. Phase 2: pw1 MFMA, output 6 primary chunks of C1/R1.
// ---------------------------------------------------------------------------
__global__ __launch_bounds__(256) void dwpw1_kernel(
    const ushort_t* __restrict__ Xc, const ushort_t* __restrict__ Xr,
    ushort_t* __restrict__ Oc, ushort_t* __restrict__ Or,
    const float* __restrict__ primary_w,
    const float* __restrict__ cheap_w,
    const float* __restrict__ bn2_s, const float* __restrict__ bn2_b,
    const float* __restrict__ bn1_s, const float* __restrict__ bn1_b)
{
    __shared__ __align__(16) ushort_t xs[128*56];
    int br = blockIdx.z, by = blockIdx.y;
    int lev, pb, HW, W, aoff, nt;
    tile_decode(blockIdx.x, lev, pb, HW, W, aoff, nt);

    const ushort_t* X = (br ? Xr : Xc) + (size_t)by*IMG6;
    ushort_t* O = (br ? Or : Oc) + (size_t)by*IMG6;
    int tid = threadIdx.x;

    dw_stage(X, xs, cheap_w, bn2_s, bn2_b, br*2, lev, pb, W, aoff, nt, tid);
    __syncthreads();

    int lane = tid & 63, wv = tid >> 6;
    int l15 = lane & 15, rg = lane >> 4;
    int pl = br*2 + 1;

    bf16x8 A[3][3];
    #pragma unroll
    for (int ot=0; ot<3; ot++)
        #pragma unroll
        for (int kt=0; kt<3; kt++)
            A[ot][kt] = ld8f(primary_w + (size_t)(pl*48 + ot*16 + l15)*96 + kt*32 + rg*8);

    #pragma unroll
    for (int i=0;i<2;i++){
        int tl = wv + i*4;
        if (tl*16 >= nt) continue;
        int a_l = tl*16 + l15;
        size_t A_g = (size_t)(aoff + pb + a_l);
        bf16x8 Bf[3];
        gather_B(X, xs, a_l, A_g, rg, Bf);
        f32x4 acc[3];
        #pragma unroll
        for (int ot=0;ot<3;ot++){ acc[ot][0]=0.f; acc[ot][1]=0.f; acc[ot][2]=0.f; acc[ot][3]=0.f; }
        #pragma unroll
        for (int kt=0;kt<3;kt++)
            #pragma unroll
            for (int ot=0;ot<3;ot++)
                acc[ot] = MFMA(A[ot][kt], Bf[kt], acc[ot]);
        #pragma unroll
        for (int ot=0;ot<3;ot++){
            f32x4 sv4 = *reinterpret_cast<const f32x4*>(bn1_s + pl*48 + ot*16 + rg*4);
            f32x4 bv4 = *reinterpret_cast<const f32x4*>(bn1_b + pl*48 + ot*16 + rg*4);
            uint2 u;
            u.x = f2bf(relu6f(fmaf(acc[ot][0], sv4[0], bv4[0])))
               | (f2bf(relu6f(fmaf(acc[ot][1], sv4[1], bv4[1]))) << 16);
            u.y = f2bf(relu6f(fmaf(acc[ot][2], sv4[2], bv4[2])))
               | (f2bf(relu6f(fmaf(acc[ot][3], sv4[3], bv4[3]))) << 16);
            int chunk = 2*ot + (rg>>1);
            *reinterpret_cast<uint2*>(O + (size_t)chunk*CHK + A_g*8 + (rg&1)*4) = u;
        }
    }
}

// ---------------------------------------------------------------------------
// Fused dw(layer1) + heads. grid (67, bc, 2): z=0 cls head on C1, z=1 reg
// head on R1. Phase 1: dw -> LDS. Phase 2: head MFMA + epilogue.
// Output stores are non-temporal (never re-read; keep L3 for intermediates).
// ---------------------------------------------------------------------------
__global__ __launch_bounds__(256) void dwhead_kernel(
    const ushort_t* __restrict__ Xc, const ushort_t* __restrict__ Xr,
    const float* __restrict__ cls_w, const float* __restrict__ obj_w,
    const float* __restrict__ reg_w,
    const float* __restrict__ cheap_w,
    const float* __restrict__ bn2_s, const float* __restrict__ bn2_b,
    const float* __restrict__ cls_b_all, const float* __restrict__ obj_b_all,
    const float* __restrict__ reg_b_all,
    float* __restrict__ scores, float* __restrict__ boxes, int b0)
{
    __shared__ __align__(16) ushort_t xs[128*56];
    int br = blockIdx.z, by = blockIdx.y;
    int lev, pb, HW, W, aoff, nt;
    tile_decode(blockIdx.x, lev, pb, HW, W, aoff, nt);

    const ushort_t* X = (br ? Xr : Xc) + (size_t)by*IMG6;
    int tid = threadIdx.x;

    dw_stage(X, xs, cheap_w, bn2_s, bn2_b, br*2 + 1, lev, pb, W, aoff, nt, tid);
    __syncthreads();

    int lane = tid & 63, wv = tid >> 6;
    int l15 = lane & 15, rg = lane >> 4;

    if (br == 0){
        // ----- cls + obj head -----
        bf16x8 A[6][3];
        #pragma unroll
        for (int ot=0; ot<5; ot++)
            #pragma unroll
            for (int kt=0; kt<3; kt++)
                A[ot][kt] = ld8f(cls_w + (size_t)(lev*80 + ot*16 + l15)*96 + kt*32 + rg*8);
        bf16x8 z8 = {0,0,0,0,0,0,0,0};
        #pragma unroll
        for (int kt=0; kt<3; kt++)
            A[5][kt] = (l15 == 0) ? ld8f(obj_w + (size_t)lev*96 + kt*32 + rg*8) : z8;
        float cb[5][4];
        #pragma unroll
        for (int ot=0; ot<5; ot++)
            #pragma unroll
            for (int j=0;j<4;j++)
                cb[ot][j] = cls_b_all[lev*80 + ot*16 + rg*4 + j];
        float obv = obj_b_all[lev];
        float* sbase = scores + (size_t)(b0 + by)*8400*80;

        #pragma unroll
        for (int i=0;i<2;i++){
            int tl = wv + i*4;
            if (tl*16 >= nt) continue;
            int a_l = tl*16 + l15;
            size_t A_g = (size_t)(aoff + pb + a_l);
            bf16x8 Bf[3];
            gather_B(X, xs, a_l, A_g, rg, Bf);
            f32x4 acc[6];
            #pragma unroll
            for (int ot=0;ot<6;ot++){ acc[ot][0]=0.f; acc[ot][1]=0.f; acc[ot][2]=0.f; acc[ot][3]=0.f; }
            #pragma unroll
            for (int kt=0;kt<3;kt++)
                #pragma unroll
                for (int ot=0;ot<6;ot++)
                    acc[ot] = MFMA(A[ot][kt], Bf[kt], acc[ot]);
            float objp = acc[5][0];
            float objv = __shfl(objp, l15) + obv;
            float* srow = sbase + A_g*80;
            #pragma unroll
            for (int ot=0;ot<5;ot++){
                f32x4 o;
                #pragma unroll
                for (int j=0;j<4;j++)
                    o[j] = sigmoidf(acc[ot][j] + cb[ot][j] + objv);
                __builtin_nontemporal_store(o, reinterpret_cast<f32x4*>(srow + ot*16 + rg*4));
            }
        }
    } else {
        // ----- reg head + DFL + boxes -----
        bf16x8 A[2][3];
        #pragma unroll
        for (int ot=0; ot<2; ot++)
            #pragma unroll
            for (int kt=0; kt<3; kt++)
                A[ot][kt] = ld8f(reg_w + (size_t)(lev*32 + ot*16 + l15)*96 + kt*32 + rg*8);
        float rb[2][4];
        #pragma unroll
        for (int ot=0; ot<2; ot++)
            #pragma unroll
            for (int j=0;j<4;j++)
                rb[ot][j] = reg_b_all[lev*32 + ot*16 + rg*4 + j];
        float sc = (lev==0) ? 8.f : (lev==1) ? 16.f : 32.f;
        float* bbase = boxes + (size_t)(b0 + by)*8400*4;

        #pragma unroll
        for (int i=0;i<2;i++){
            int tl = wv + i*4;
            if (tl*16 >= nt) continue;
            int a_l = tl*16 + l15;
            size_t A_g = (size_t)(aoff + pb + a_l);
            bf16x8 Bf[3];
            gather_B(X, xs, a_l, A_g, rg, Bf);
            f32x4 acc[2];
            #pragma unroll
            for (int ot=0;ot<2;ot++){ acc[ot][0]=0.f; acc[ot][1]=0.f; acc[ot][2]=0.f; acc[ot][3]=0.f; }
            #pragma unroll
            for (int kt=0;kt<3;kt++)
                #pragma unroll
                for (int ot=0;ot<2;ot++)
                    acc[ot] = MFMA(A[ot][kt], Bf[kt], acc[ot]);

            float rbase = (float)((rg & 1) * 4);
            float lv[2];
            #pragma unroll
            for (int ot=0;ot<2;ot++){
                float tv[4];
                #pragma unroll
                for (int j=0;j<4;j++) tv[j] = acc[ot][j] + rb[ot][j];
                float m = fmaxf(fmaxf(tv[0],tv[1]), fmaxf(tv[2],tv[3]));
                m = fmaxf(m, __shfl_xor(m, 16));
                float se = 0.f, ne = 0.f;
                #pragma unroll
                for (int j=0;j<4;j++){
                    float e = __expf(tv[j] - m);
                    se += e; ne = fmaf(e, rbase + (float)j, ne);
                }
                float den = se + __shfl_xor(se, 16);
                float num = ne + __shfl_xor(ne, 16);
                lv[ot] = num / den * sc;
            }
            int p = pb + a_l;
            int hh = (lev==0) ? p/80 : (lev==1) ? p/40 : p/20;
            int xx = p - hh*W;
            float ax = (xx + 0.5f)*sc, ay = (hh + 0.5f)*sc;
            float v0 = ax - lv[0];
            float v1 = ax + lv[1];
            float w0 = ay - lv[0];
            float w1 = ay + lv[1];
            float y1g = __shfl_xor(w0, 32);
            float y2g = __shfl_xor(w1, 32);
            if (lane < 16){
                f32x4 o; o[0] = v0; o[1] = y1g; o[2] = v1; o[3] = y2g;
                __builtin_nontemporal_store(o, reinterpret_cast<f32x4*>(bbase + A_g*4));
            }
        }
    }
}

// ---------------------------------------------------------------------------
extern "C" void kernel_launch(void* const* d_in, const int* in_sizes, int n_in,
                              void* d_out, int out_size, void* d_ws, size_t ws_size,
                              hipStream_t stream)
{
    const float* f0        = (const float*)d_in[0];
    const float* f1        = (const float*)d_in[1];
    const float* f2        = (const float*)d_in[2];
    const float* primary_w = (const float*)d_in[3];
    const float* bn1_s     = (const float*)d_in[4];
    const float* bn1_b     = (const float*)d_in[5];
    const float* cheap_w   = (const float*)d_in[6];
    const float* bn2_s     = (const float*)d_in[7];
    const float* bn2_b     = (const float*)d_in[8];
    const float* cls_w     = (const float*)d_in[9];
    const float* cls_b     = (const float*)d_in[10];
    const float* obj_w     = (const float*)d_in[11];
    const float* obj_b     = (const float*)d_in[12];
    const float* reg_w     = (const float*)d_in[13];
    const float* reg_b     = (const float*)d_in[14];

    const int B = 16;
    float* boxes  = (float*)d_out;
    float* scores = boxes + (size_t)16*8400*4;

    int bc = 16;
    while (bc > 1 && 4*(size_t)bc*IMG6*2 > ws_size) bc >>= 1;
    size_t perBuf = (size_t)bc*IMG6;
    ushort_t* C0 = (ushort_t*)d_ws;
    ushort_t* R0 = C0 + perBuf;
    ushort_t* C1 = R0 + perBuf;
    ushort_t* R1 = C1 + perBuf;

    for (int b0 = 0; b0 < B; b0 += bc){
        pw0_kernel<<<dim3(132, bc), 256, 0, stream>>>(
            f0, f1, f2, C0, R0, primary_w, bn1_s, bn1_b, b0);
        dwpw1_kernel<<<dim3(67, bc, 2), 256, 0, stream>>>(
            C0, R0, C1, R1, primary_w, cheap_w, bn2_s, bn2_b, bn1_s, bn1_b);
        dwhead_kernel<<<dim3(67, bc, 2), 256, 0, stream>>>(
            C1, R1, cls_w, obj_w, reg_w, cheap_w, bn2_s, bn2_b,
            cls_b, obj_b, reg_b, scores, boxes, b0);
    }
}

// Round 13
// 88.450 us; speedup vs baseline: 1.5913x; 1.5913x over previous
//
#include <hip/hip_runtime.h>
#include <math.h>

typedef unsigned short ushort_t;
typedef __attribute__((ext_vector_type(8))) short bf16x8;
typedef __attribute__((ext_vector_type(4))) float f32x4;

#define CHK 67200            // chunk plane stride in ushorts (8400 anchors * 8 ch)
#define IMG6 403200          // per-image buffer: 6 primary chunks only

__device__ __forceinline__ float relu6f(float x){ return fminf(fmaxf(x,0.f),6.f); }
__device__ __forceinline__ float sigmoidf(float x){ return 1.f/(1.f+__expf(-x)); }
__device__ __forceinline__ float bf2f(unsigned u){ union{unsigned i; float f;}v; v.i=u<<16; return v.f; }
__device__ __forceinline__ unsigned f2bf(float f){ union{float f; unsigned i;}v; v.f=f;
    unsigned r = v.i + 0x7fff + ((v.i>>16)&1); return r>>16; }
__device__ __forceinline__ bf16x8 ldb8(const ushort_t* p){ return *reinterpret_cast<const bf16x8*>(p); }
#define MFMA(a,b,c) __builtin_amdgcn_mfma_f32_16x16x32_bf16((a),(b),(c),0,0,0)

// ---------------------------------------------------------------------------
// Weight prep (runs once): fp32 -> bf16.
// ---------------------------------------------------------------------------
__global__ __launch_bounds__(256) void prep_kernel(
    const float* __restrict__ primary_w, const float* __restrict__ cls_w,
    const float* __restrict__ obj_w, const float* __restrict__ reg_w,
    ushort_t* __restrict__ pwW, ushort_t* __restrict__ clsW, ushort_t* __restrict__ regW)
{
    int i = blockIdx.x*256 + threadIdx.x;
    if (i < 18432) pwW[i] = (ushort_t)f2bf(primary_w[i]);
    if (i < 27648){
        int lev = i/9216, rem = i - lev*9216, row = rem/96, c = rem - row*96;
        float v = (row < 80) ? cls_w[(lev*80 + row)*96 + c]
                : (row == 80) ? obj_w[lev*96 + c] : 0.f;
        clsW[i] = (ushort_t)f2bf(v);
    }
    if (i < 9216) regW[i] = (ushort_t)f2bf(reg_w[i]);
}

// ---------------------------------------------------------------------------
// Tile decode: 67 blocks of 128 anchors (50 lev0 / 13 lev1 / 4 lev2).
// ---------------------------------------------------------------------------
__device__ __forceinline__ void tile_decode(int bx, int& lev, int& pb, int& HW,
                                            int& W, int& aoff, int& nt)
{
    if (bx < 50){ lev=0; pb = bx*128;      HW=6400; W=80; aoff=0;    }
    else if (bx < 63){ lev=1; pb = (bx-50)*128; HW=1600; W=40; aoff=6400; }
    else { lev=2; pb = (bx-63)*128; HW=400; W=20; aoff=8000; }
    nt = HW - pb; if (nt > 128) nt = 128;
}

// ---------------------------------------------------------------------------
// dw stage: 3x3 depthwise on 6 primary chunks of X (global, halo ok) for a
// 128-anchor tile -> cheap 48ch into LDS xs[a][56] (slots 0..5 of 8ch).
// 192 threads active: ck = tid>>5 (chunk), q = tid&31 (anchor quad).
// ---------------------------------------------------------------------------
__device__ __forceinline__ void dw_stage(
    const ushort_t* __restrict__ X, ushort_t* __restrict__ xs,
    const float* __restrict__ cheap_w,
    const float* __restrict__ bn2_s, const float* __restrict__ bn2_b,
    int pl, int lev, int pb, int W, int aoff, int nt, int tid)
{
    int ck = tid >> 5;          // 0..7 (6 used)
    int q  = tid & 31;
    if (ck >= 6 || q*4 >= nt) return;
    int p = pb + q*4;
    int h = (lev==0) ? p/80 : (lev==1) ? p/40 : p/20;
    int x0 = p - h*W;           // multiple of 4; 4 anchors same row
    int s8 = ck*8;
    const ushort_t* src = X + (size_t)ck*CHK + (size_t)(aoff+p)*8;

    float acc[4][8];
    #pragma unroll
    for (int j=0;j<4;j++)
        #pragma unroll
        for (int c=0;c<8;c++) acc[j][c] = 0.f;

    #pragma unroll
    for (int dy=-1; dy<=1; dy++){
        int hh = h + dy;
        bool rv = (unsigned)hh < (unsigned)W;    // H == W (square levels)
        float xv[6][8];
        #pragma unroll
        for (int i=0;i<6;i++){
            int px = x0 + i - 1;
            bool v = rv && ((unsigned)px < (unsigned)W);
            ptrdiff_t off = v ? (ptrdiff_t)(dy*W + i - 1)*8 : 0;    // address select
            uint4 u = *reinterpret_cast<const uint4*>(src + off);   // unconditional
            u.x = v ? u.x : 0u; u.y = v ? u.y : 0u;
            u.z = v ? u.z : 0u; u.w = v ? u.w : 0u;
            xv[i][0]=bf2f(u.x&0xffffu); xv[i][1]=bf2f(u.x>>16);
            xv[i][2]=bf2f(u.y&0xffffu); xv[i][3]=bf2f(u.y>>16);
            xv[i][4]=bf2f(u.z&0xffffu); xv[i][5]=bf2f(u.z>>16);
            xv[i][6]=bf2f(u.w&0xffffu); xv[i][7]=bf2f(u.w>>16);
        }
        #pragma unroll
        for (int c=0;c<8;c++){
            float w0 = cheap_w[(pl*48 + s8 + c)*9 + (dy+1)*3 + 0];
            float w1 = cheap_w[(pl*48 + s8 + c)*9 + (dy+1)*3 + 1];
            float w2 = cheap_w[(pl*48 + s8 + c)*9 + (dy+1)*3 + 2];
            #pragma unroll
            for (int j=0;j<4;j++)
                acc[j][c] = fmaf(xv[j][c], w0,
                            fmaf(xv[j+1][c], w1,
                            fmaf(xv[j+2][c], w2, acc[j][c])));
        }
    }

    float s2v[8], b2v[8];
    #pragma unroll
    for (int c=0;c<8;c++){
        s2v[c] = bn2_s[pl*48 + s8 + c];
        b2v[c] = bn2_b[pl*48 + s8 + c];
    }
    #pragma unroll
    for (int j=0;j<4;j++){
        uint4 o;
        o.x = f2bf(relu6f(fmaf(acc[j][0], s2v[0], b2v[0])))
           | (f2bf(relu6f(fmaf(acc[j][1], s2v[1], b2v[1]))) << 16);
        o.y = f2bf(relu6f(fmaf(acc[j][2], s2v[2], b2v[2])))
           | (f2bf(relu6f(fmaf(acc[j][3], s2v[3], b2v[3]))) << 16);
        o.z = f2bf(relu6f(fmaf(acc[j][4], s2v[4], b2v[4])))
           | (f2bf(relu6f(fmaf(acc[j][5], s2v[5], b2v[5]))) << 16);
        o.w = f2bf(relu6f(fmaf(acc[j][6], s2v[6], b2v[6])))
           | (f2bf(relu6f(fmaf(acc[j][7], s2v[7], b2v[7]))) << 16);
        *reinterpret_cast<uint4*>(xs + (size_t)(q*4+j)*56 + s8) = o;
    }
}

// B-fragment gather: primary from global chunks, cheap from LDS.
__device__ __forceinline__ void gather_B(
    const ushort_t* __restrict__ X, const ushort_t* __restrict__ xs,
    int a_l, size_t A_g, int rg, bf16x8* Bf)
{
    Bf[0] = ldb8(X + (size_t)rg*CHK + A_g*8);
    Bf[1] = (rg < 2) ? ldb8(X + (size_t)(4+rg)*CHK + A_g*8)
                     : ldb8(xs + (size_t)a_l*56 + (rg-2)*8);
    Bf[2] = ldb8(xs + (size_t)a_l*56 + 16 + rg*8);
}

// ---------------------------------------------------------------------------
// Layer-0 pointwise via MFMA, LDS-free gather from CHW fp32.
// grid (132, bc), block 256; ONE 16-anchor tile per wave (2112 blocks at
// bc=16 -> ~8 blocks/CU, short dependent chains).
// Output: 6 primary chunks of C0/R0.
// ---------------------------------------------------------------------------
__global__ __launch_bounds__(256) void pw0_kernel(
    const float* __restrict__ f0, const float* __restrict__ f1, const float* __restrict__ f2,
    ushort_t* __restrict__ Oc, ushort_t* __restrict__ Or,
    const ushort_t* __restrict__ pwW,
    const float* __restrict__ bn1_s, const float* __restrict__ bn1_b, int b0)
{
    int lane = threadIdx.x & 63, wv = threadIdx.x >> 6;
    int l15 = lane & 15, rg = lane >> 4;
    int by = blockIdx.y;

    bf16x8 A[2][3][3];
    #pragma unroll
    for (int br=0;br<2;br++)
        #pragma unroll
        for (int ot=0; ot<3; ot++)
            #pragma unroll
            for (int kt=0; kt<3; kt++)
                A[br][ot][kt] = ldb8(pwW + (size_t)(br*96 + ot*16 + l15)*96 + kt*32 + rg*8);

    int t = blockIdx.x*4 + wv;          // one tile per wave
    if (t >= 525) return;
    int lev  = (t < 400) ? 0 : (t < 500) ? 1 : 2;
    int HW   = (lev==0) ? 6400 : (lev==1) ? 1600 : 400;
    int tb   = (lev==0) ? 0    : (lev==1) ? 400  : 500;
    int aoff = (lev==0) ? 0    : (lev==1) ? 6400 : 8000;
    int p0   = (t - tb)*16;
    const float* fb = ((lev==0)? f0 : (lev==1)? f1 : f2)
                    + (size_t)(b0+by)*96*HW + p0 + l15;

    bf16x8 Bf[3];
    #pragma unroll
    for (int kt=0;kt<3;kt++){
        const float* fc = fb + (size_t)(kt*32 + rg*8)*HW;
        float x[8];
        #pragma unroll
        for (int j=0;j<8;j++) x[j] = fc[(size_t)j*HW];
        union { unsigned u[4]; bf16x8 v; } cv;
        #pragma unroll
        for (int j=0;j<4;j++) cv.u[j] = f2bf(x[2*j]) | (f2bf(x[2*j+1])<<16);
        Bf[kt] = cv.v;
    }

    size_t A_g = (size_t)(aoff + p0 + l15);
    #pragma unroll
    for (int br=0;br<2;br++){
        int pl = br*2;
        f32x4 acc[3];
        #pragma unroll
        for (int ot=0;ot<3;ot++){ acc[ot][0]=0.f; acc[ot][1]=0.f; acc[ot][2]=0.f; acc[ot][3]=0.f; }
        #pragma unroll
        for (int kt=0;kt<3;kt++)
            #pragma unroll
            for (int ot=0;ot<3;ot++)
                acc[ot] = MFMA(A[br][ot][kt], Bf[kt], acc[ot]);
        ushort_t* obase = (br ? Or : Oc) + (size_t)by*IMG6;
        #pragma unroll
        for (int ot=0;ot<3;ot++){
            f32x4 sv4 = *reinterpret_cast<const f32x4*>(bn1_s + pl*48 + ot*16 + rg*4);
            f32x4 bv4 = *reinterpret_cast<const f32x4*>(bn1_b + pl*48 + ot*16 + rg*4);
            uint2 u;
            u.x = f2bf(relu6f(fmaf(acc[ot][0], sv4[0], bv4[0])))
               | (f2bf(relu6f(fmaf(acc[ot][1], sv4[1], bv4[1]))) << 16);
            u.y = f2bf(relu6f(fmaf(acc[ot][2], sv4[2], bv4[2])))
               | (f2bf(relu6f(fmaf(acc[ot][3], sv4[3], bv4[3]))) << 16);
            int chunk = 2*ot + (rg>>1);
            *reinterpret_cast<uint2*>(obase + (size_t)chunk*CHK + A_g*8 + (rg&1)*4) = u;
        }
    }
}

// ---------------------------------------------------------------------------
// Fused dw(layer0) + pw(layer1). grid (67, bc, 2), block 256.
// Phase 1: dw -> LDS. Phase 2: pw1 MFMA, output 6 primary chunks of C1/R1.
// ---------------------------------------------------------------------------
__global__ __launch_bounds__(256) void dwpw1_kernel(
    const ushort_t* __restrict__ Xc, const ushort_t* __restrict__ Xr,
    ushort_t* __restrict__ Oc, ushort_t* __restrict__ Or,
    const ushort_t* __restrict__ pwW,
    const float* __restrict__ cheap_w,
    const float* __restrict__ bn2_s, const float* __restrict__ bn2_b,
    const float* __restrict__ bn1_s, const float* __restrict__ bn1_b)
{
    __shared__ __align__(16) ushort_t xs[128*56];
    int br = blockIdx.z, by = blockIdx.y;
    int lev, pb, HW, W, aoff, nt;
    tile_decode(blockIdx.x, lev, pb, HW, W, aoff, nt);

    const ushort_t* X = (br ? Xr : Xc) + (size_t)by*IMG6;
    ushort_t* O = (br ? Or : Oc) + (size_t)by*IMG6;
    int tid = threadIdx.x;

    dw_stage(X, xs, cheap_w, bn2_s, bn2_b, br*2, lev, pb, W, aoff, nt, tid);
    __syncthreads();

    int lane = tid & 63, wv = tid >> 6;
    int l15 = lane & 15, rg = lane >> 4;
    int pl = br*2 + 1;
    const ushort_t* Wp = pwW + (size_t)pl*48*96;

    bf16x8 A[3][3];
    #pragma unroll
    for (int ot=0; ot<3; ot++)
        #pragma unroll
        for (int kt=0; kt<3; kt++)
            A[ot][kt] = ldb8(Wp + (size_t)(ot*16 + l15)*96 + kt*32 + rg*8);

    #pragma unroll
    for (int i=0;i<2;i++){
        int tl = wv + i*4;
        if (tl*16 >= nt) continue;
        int a_l = tl*16 + l15;
        size_t A_g = (size_t)(aoff + pb + a_l);
        bf16x8 Bf[3];
        gather_B(X, xs, a_l, A_g, rg, Bf);
        f32x4 acc[3];
        #pragma unroll
        for (int ot=0;ot<3;ot++){ acc[ot][0]=0.f; acc[ot][1]=0.f; acc[ot][2]=0.f; acc[ot][3]=0.f; }
        #pragma unroll
        for (int kt=0;kt<3;kt++)
            #pragma unroll
            for (int ot=0;ot<3;ot++)
                acc[ot] = MFMA(A[ot][kt], Bf[kt], acc[ot]);
        #pragma unroll
        for (int ot=0;ot<3;ot++){
            f32x4 sv4 = *reinterpret_cast<const f32x4*>(bn1_s + pl*48 + ot*16 + rg*4);
            f32x4 bv4 = *reinterpret_cast<const f32x4*>(bn1_b + pl*48 + ot*16 + rg*4);
            uint2 u;
            u.x = f2bf(relu6f(fmaf(acc[ot][0], sv4[0], bv4[0])))
               | (f2bf(relu6f(fmaf(acc[ot][1], sv4[1], bv4[1]))) << 16);
            u.y = f2bf(relu6f(fmaf(acc[ot][2], sv4[2], bv4[2])))
               | (f2bf(relu6f(fmaf(acc[ot][3], sv4[3], bv4[3]))) << 16);
            int chunk = 2*ot + (rg>>1);
            *reinterpret_cast<uint2*>(O + (size_t)chunk*CHK + A_g*8 + (rg&1)*4) = u;
        }
    }
}

// ---------------------------------------------------------------------------
// Fused dw(layer1) + heads. grid (67, bc, 2): z=0 cls head on C1, z=1 reg
// head on R1. Phase 1: dw -> LDS. Phase 2: head MFMA + epilogue.
// ---------------------------------------------------------------------------
__global__ __launch_bounds__(256) void dwhead_kernel(
    const ushort_t* __restrict__ Xc, const ushort_t* __restrict__ Xr,
    const ushort_t* __restrict__ clsW, const ushort_t* __restrict__ regW,
    const float* __restrict__ cheap_w,
    const float* __restrict__ bn2_s, const float* __restrict__ bn2_b,
    const float* __restrict__ cls_b_all, const float* __restrict__ obj_b_all,
    const float* __restrict__ reg_b_all,
    float* __restrict__ scores, float* __restrict__ boxes, int b0)
{
    __shared__ __align__(16) ushort_t xs[128*56];
    int br = blockIdx.z, by = blockIdx.y;
    int lev, pb, HW, W, aoff, nt;
    tile_decode(blockIdx.x, lev, pb, HW, W, aoff, nt);

    const ushort_t* X = (br ? Xr : Xc) + (size_t)by*IMG6;
    int tid = threadIdx.x;

    dw_stage(X, xs, cheap_w, bn2_s, bn2_b, br*2 + 1, lev, pb, W, aoff, nt, tid);
    __syncthreads();

    int lane = tid & 63, wv = tid >> 6;
    int l15 = lane & 15, rg = lane >> 4;

    if (br == 0){
        // ----- cls + obj head -----
        const ushort_t* Wl = clsW + (size_t)lev*96*96;
        bf16x8 A[6][3];
        #pragma unroll
        for (int ot=0; ot<6; ot++)
            #pragma unroll
            for (int kt=0; kt<3; kt++)
                A[ot][kt] = ldb8(Wl + (size_t)(ot*16 + l15)*96 + kt*32 + rg*8);
        float cb[5][4];
        #pragma unroll
        for (int ot=0; ot<5; ot++)
            #pragma unroll
            for (int j=0;j<4;j++)
                cb[ot][j] = cls_b_all[lev*80 + ot*16 + rg*4 + j];
        float obv = obj_b_all[lev];
        float* sbase = scores + (size_t)(b0 + by)*8400*80;

        #pragma unroll
        for (int i=0;i<2;i++){
            int tl = wv + i*4;
            if (tl*16 >= nt) continue;
            int a_l = tl*16 + l15;
            size_t A_g = (size_t)(aoff + pb + a_l);
            bf16x8 Bf[3];
            gather_B(X, xs, a_l, A_g, rg, Bf);
            f32x4 acc[6];
            #pragma unroll
            for (int ot=0;ot<6;ot++){ acc[ot][0]=0.f; acc[ot][1]=0.f; acc[ot][2]=0.f; acc[ot][3]=0.f; }
            #pragma unroll
            for (int kt=0;kt<3;kt++)
                #pragma unroll
                for (int ot=0;ot<6;ot++)
                    acc[ot] = MFMA(A[ot][kt], Bf[kt], acc[ot]);
            float objp = acc[5][0];
            float objv = __shfl(objp, l15) + obv;
            float* srow = sbase + A_g*80;
            #pragma unroll
            for (int ot=0;ot<5;ot++){
                f32x4 o;
                #pragma unroll
                for (int j=0;j<4;j++)
                    o[j] = sigmoidf(acc[ot][j] + cb[ot][j] + objv);
                *reinterpret_cast<f32x4*>(srow + ot*16 + rg*4) = o;
            }
        }
    } else {
        // ----- reg head + DFL + boxes -----
        const ushort_t* Wl = regW + (size_t)lev*32*96;
        bf16x8 A[2][3];
        #pragma unroll
        for (int ot=0; ot<2; ot++)
            #pragma unroll
            for (int kt=0; kt<3; kt++)
                A[ot][kt] = ldb8(Wl + (size_t)(ot*16 + l15)*96 + kt*32 + rg*8);
        float rb[2][4];
        #pragma unroll
        for (int ot=0; ot<2; ot++)
            #pragma unroll
            for (int j=0;j<4;j++)
                rb[ot][j] = reg_b_all[lev*32 + ot*16 + rg*4 + j];
        float sc = (lev==0) ? 8.f : (lev==1) ? 16.f : 32.f;
        float* bbase = boxes + (size_t)(b0 + by)*8400*4;

        #pragma unroll
        for (int i=0;i<2;i++){
            int tl = wv + i*4;
            if (tl*16 >= nt) continue;
            int a_l = tl*16 + l15;
            size_t A_g = (size_t)(aoff + pb + a_l);
            bf16x8 Bf[3];
            gather_B(X, xs, a_l, A_g, rg, Bf);
            f32x4 acc[2];
            #pragma unroll
            for (int ot=0;ot<2;ot++){ acc[ot][0]=0.f; acc[ot][1]=0.f; acc[ot][2]=0.f; acc[ot][3]=0.f; }
            #pragma unroll
            for (int kt=0;kt<3;kt++)
                #pragma unroll
                for (int ot=0;ot<2;ot++)
                    acc[ot] = MFMA(A[ot][kt], Bf[kt], acc[ot]);

            float rbase = (float)((rg & 1) * 4);
            float lv[2];
            #pragma unroll
            for (int ot=0;ot<2;ot++){
                float tv[4];
                #pragma unroll
                for (int j=0;j<4;j++) tv[j] = acc[ot][j] + rb[ot][j];
                float m = fmaxf(fmaxf(tv[0],tv[1]), fmaxf(tv[2],tv[3]));
                m = fmaxf(m, __shfl_xor(m, 16));
                float se = 0.f, ne = 0.f;
                #pragma unroll
                for (int j=0;j<4;j++){
                    float e = __expf(tv[j] - m);
                    se += e; ne = fmaf(e, rbase + (float)j, ne);
                }
                float den = se + __shfl_xor(se, 16);
                float num = ne + __shfl_xor(ne, 16);
                lv[ot] = num / den * sc;
            }
            int p = pb + a_l;
            int hh = (lev==0) ? p/80 : (lev==1) ? p/40 : p/20;
            int xx = p - hh*W;
            float ax = (xx + 0.5f)*sc, ay = (hh + 0.5f)*sc;
            float v0 = ax - lv[0];
            float v1 = ax + lv[1];
            float w0 = ay - lv[0];
            float w1 = ay + lv[1];
            float y1g = __shfl_xor(w0, 32);
            float y2g = __shfl_xor(w1, 32);
            if (lane < 16){
                f32x4 o; o[0] = v0; o[1] = y1g; o[2] = v1; o[3] = y2g;
                *reinterpret_cast<f32x4*>(bbase + A_g*4) = o;
            }
        }
    }
}

// ---------------------------------------------------------------------------
extern "C" void kernel_launch(void* const* d_in, const int* in_sizes, int n_in,
                              void* d_out, int out_size, void* d_ws, size_t ws_size,
                              hipStream_t stream)
{
    const float* f0        = (const float*)d_in[0];
    const float* f1        = (const float*)d_in[1];
    const float* f2        = (const float*)d_in[2];
    const float* primary_w = (const float*)d_in[3];
    const float* bn1_s     = (const float*)d_in[4];
    const float* bn1_b     = (const float*)d_in[5];
    const float* cheap_w   = (const float*)d_in[6];
    const float* bn2_s     = (const float*)d_in[7];
    const float* bn2_b     = (const float*)d_in[8];
    const float* cls_w     = (const float*)d_in[9];
    const float* cls_b     = (const float*)d_in[10];
    const float* obj_w     = (const float*)d_in[11];
    const float* obj_b     = (const float*)d_in[12];
    const float* reg_w     = (const float*)d_in[13];
    const float* reg_b     = (const float*)d_in[14];

    const int B = 16;
    float* boxes  = (float*)d_out;
    float* scores = boxes + (size_t)16*8400*4;

    ushort_t* pwW  = (ushort_t*)d_ws;
    ushort_t* clsW = pwW + 18432;
    ushort_t* regW = clsW + 27648;
    ushort_t* bufs = regW + 9216;
    size_t used0 = (size_t)55296*2;

    int bc = 16;
    while (bc > 1 && used0 + 4*(size_t)bc*IMG6*2 > ws_size) bc >>= 1;
    size_t perBuf = (size_t)bc*IMG6;
    ushort_t* C0 = bufs;
    ushort_t* R0 = C0 + perBuf;
    ushort_t* C1 = R0 + perBuf;
    ushort_t* R1 = C1 + perBuf;

    prep_kernel<<<108, 256, 0, stream>>>(primary_w, cls_w, obj_w, reg_w, pwW, clsW, regW);

    for (int b0 = 0; b0 < B; b0 += bc){
        pw0_kernel<<<dim3(132, bc), 256, 0, stream>>>(
            f0, f1, f2, C0, R0, pwW, bn1_s, bn1_b, b0);
        dwpw1_kernel<<<dim3(67, bc, 2), 256, 0, stream>>>(
            C0, R0, C1, R1, pwW, cheap_w, bn2_s, bn2_b, bn1_s, bn1_b);
        dwhead_kernel<<<dim3(67, bc, 2), 256, 0, stream>>>(
            C1, R1, clsW, regW, cheap_w, bn2_s, bn2_b,
            cls_b, obj_b, reg_b, scores, boxes, b0);
    }
}